// Round 8
// baseline (272.112 us; speedup 1.0000x reference)
//
#include <hip/hip_runtime.h>

typedef unsigned short ushort_t;
typedef short short8 __attribute__((ext_vector_type(8)));
typedef float float4v __attribute__((ext_vector_type(4)));

__device__ __forceinline__ float bf2f(ushort_t u) {
    union { unsigned int i; float f; } x; x.i = ((unsigned int)u) << 16; return x.f;
}
__device__ __forceinline__ ushort_t f2bf(float f) {
    unsigned int u = __float_as_uint(f);
    unsigned int r = (u + 0x7FFFu + ((u >> 16) & 1u)) >> 16;
    return (ushort_t)r;
}
__device__ __forceinline__ void store_out(float* p, float v) { *p = v; }
__device__ __forceinline__ void store_out(ushort_t* p, float v) { *p = f2bf(v); }

// async global->LDS 16B/lane; lds ptr must be wave-uniform base (lane*16 auto)
__device__ __forceinline__ void gll16(const ushort_t* g, ushort_t* l) {
    __builtin_amdgcn_global_load_lds(
        (const __attribute__((address_space(1))) void*)g,
        (__attribute__((address_space(3))) void*)l, 16, 0, 0);
}

// ---------------------------------------------------------------------------
// Fallback input-dtype detection (only launched when in_sizes is ambiguous).
// ---------------------------------------------------------------------------
__global__ void detect_dtype(const ushort_t* __restrict__ tgt, int* __restrict__ flag) {
    __shared__ int red[256];
    const int tid = threadIdx.x;
    int p = 0;
    for (int i = tid; i < 512; i += 256) {
        ushort_t u = tgt[i];
        int e = (u >> 7) & 0xFF;
        if (u == 0 || (e >= 100 && e <= 140)) ++p;
    }
    red[tid] = p; __syncthreads();
    for (int off = 128; off > 0; off >>= 1) {
        if (tid < off) red[tid] += red[tid + off];
        __syncthreads();
    }
    if (tid == 0) flag[0] = (red[0] >= 480) ? 1 : 0;
}

__device__ __forceinline__ bool is_f32(int mode, const int* dflag) {
    return (mode == 2) ? (dflag[0] == 0) : (mode == 0);
}

// ---------------------------------------------------------------------------
// Unified prep, exact flat grid of 3098 blocks (unchanged from round 7).
// ---------------------------------------------------------------------------
__global__ __launch_bounds__(256) void prep_all(
    const void* sWq, const void* sWk, const void* sWv, const void* sWo,
    const void* cWq, const void* cWk, const void* cWv, const void* cWo,
    const void* fW1, const void* fW2,
    const void* tgt, const void* mem,
    const void* sbq, const void* sbk, const void* sbv, const void* sbo,
    const void* cbq, const void* cbk, const void* cbv, const void* cbo,
    const void* fb1, const void* fb2,
    ushort_t* __restrict__ wb, ushort_t* __restrict__ tb, ushort_t* __restrict__ mb,
    float* __restrict__ pb, int mode, const int* __restrict__ dflag)
{
    const bool f32 = is_f32(mode, dflag);
    const int tid = threadIdx.x;
    const int id = blockIdx.x;

    if (id < 1024) {
        int z, kt, nt;
        if (id < 512)      { z = id >> 6;  int t = id & 63;  kt = t >> 3; nt = t & 7;  }
        else if (id < 768) { z = 8;        int t = id - 512; kt = t >> 5; nt = t & 31; }
        else               { z = 9;        int t = id - 768; kt = t >> 3; nt = t & 7;  }
        const void* src; ushort_t* dst; int Kd, Nd;
        switch (z) {
            case 0: src = sWq; dst = wb + 0;       Kd = 512;  Nd = 512;  break;
            case 1: src = sWk; dst = wb + 262144;  Kd = 512;  Nd = 512;  break;
            case 2: src = sWv; dst = wb + 524288;  Kd = 512;  Nd = 512;  break;
            case 3: src = sWo; dst = wb + 786432;  Kd = 512;  Nd = 512;  break;
            case 4: src = cWq; dst = wb + 1048576; Kd = 512;  Nd = 512;  break;
            case 5: src = cWk; dst = wb + 1310720; Kd = 512;  Nd = 512;  break;
            case 6: src = cWv; dst = wb + 1572864; Kd = 512;  Nd = 512;  break;
            case 7: src = cWo; dst = wb + 1835008; Kd = 512;  Nd = 512;  break;
            case 8: src = fW1; dst = wb + 2097152; Kd = 512;  Nd = 2048; break;
            default:src = fW2; dst = wb + 3145728; Kd = 2048; Nd = 512;  break;
        }
        const int k0 = kt * 64, n0 = nt * 64;
        __shared__ ushort_t T[64][65];
#pragma unroll
        for (int i = 0; i < 16; ++i) {
            int j = i * 256 + tid;
            int r = j >> 6, c = j & 63;
            float v = f32 ? ((const float*)src)[(size_t)(k0 + r) * Nd + n0 + c]
                          : bf2f(((const ushort_t*)src)[(size_t)(k0 + r) * Nd + n0 + c]);
            T[r][c] = f2bf(v);
        }
        __syncthreads();
#pragma unroll
        for (int i = 0; i < 16; ++i) {
            int j = i * 256 + tid;
            int n = j >> 6, k = j & 63;
            dst[(size_t)(n0 + n) * Kd + k0 + k] = T[k][n];
        }
        return;
    }

    if (id < 3072) {
        const int bid0 = id - 1024;
        const void* src = (bid0 < 1024) ? tgt : mem;
        ushort_t* dst = (bid0 < 1024) ? tb : mb;
        const int bid = bid0 & 1023;
        const int i = (bid * 256 + tid) * 8;
        if (f32) {
            float4 v0 = *(const float4*)((const float*)src + i);
            float4 v1 = *(const float4*)((const float*)src + i + 4);
            ushort_t o[8] = { f2bf(v0.x), f2bf(v0.y), f2bf(v0.z), f2bf(v0.w),
                              f2bf(v1.x), f2bf(v1.y), f2bf(v1.z), f2bf(v1.w) };
            *(uint4*)(dst + i) = *(const uint4*)o;
        } else {
            *(uint4*)(dst + i) = *(const uint4*)((const ushort_t*)src + i);
        }
        return;
    }

    {
        const int i = (id - 3072) * 256 + tid;
        if (i >= 6656) return;
        const void* src; int off;
        if      (i < 512)  { src = sbq; off = i; }
        else if (i < 1024) { src = sbk; off = i - 512; }
        else if (i < 1536) { src = sbv; off = i - 1024; }
        else if (i < 2048) { src = sbo; off = i - 1536; }
        else if (i < 2560) { src = cbq; off = i - 2048; }
        else if (i < 3072) { src = cbk; off = i - 2560; }
        else if (i < 3584) { src = cbv; off = i - 3072; }
        else if (i < 4096) { src = cbo; off = i - 3584; }
        else if (i < 6144) { src = fb1; off = i - 4096; }
        else               { src = fb2; off = i - 6144; }
        pb[i] = f32 ? ((const float*)src)[off] : bf2f(((const ushort_t*)src)[off]);
    }
}

// ---------------------------------------------------------------------------
// GEMM body as a device function (pool-based LDS), used by the merged
// o-proj+crossKV kernel. Identical schedule to gemm_tn.
// ---------------------------------------------------------------------------
template<typename OutT, bool RELU, int BM, int BN, bool KSPLIT>
__device__ __forceinline__ void gemm_body(ushort_t* pool, int bx, int by, int bz,
    const ushort_t* __restrict__ A1, const ushort_t* __restrict__ A2,
    int ySplit, int lda,
    const ushort_t* __restrict__ Wt, int ldw,
    const float* __restrict__ bias,
    OutT* __restrict__ C, int ldc, int K,
    OutT* __restrict__ C2)
{
    constexpr int WC = (BM == 64 && BN == 128) ? 4 : 2;
    constexpr int WR = 4 / WC;
    constexpr int MI = BM / (WR * 16);
    constexpr int NI = BN / (WC * 16);
    ushort_t* Asp = pool;                 // [2][2][BM][32]
    ushort_t* Bsp = pool + 128 * BM;      // [2][2][BN][32]

    const int tid = threadIdx.x;
    const int wave = tid >> 6, lane = tid & 63;
    const int quad = lane >> 4, l16 = lane & 15;
    const int m0 = bx * BM, n0 = by * BN;
    const int wm = (wave / WC) * (BM / WR);
    const int wn = (wave % WC) * (BN / WC);
    const ushort_t* A = (by < ySplit) ? A1 : A2;
    const ushort_t* W = Wt;
    OutT* Cw = C;
    bool second = false;
    if (KSPLIT && bz) { A += K; W += K; Cw = C2; second = true; }

    float4v acc[MI][NI];
#pragma unroll
    for (int mi = 0; mi < MI; ++mi)
#pragma unroll
        for (int ni = 0; ni < NI; ++ni) {
            acc[mi][ni][0] = 0.f; acc[mi][ni][1] = 0.f;
            acc[mi][ni][2] = 0.f; acc[mi][ni][3] = 0.f;
        }

    const int srow = lane >> 2;
    const int scc  = lane & 3;
    const int sg   = (scc - (lane >> 3)) & 3;
    const ushort_t* aptr0 = A + (size_t)(m0 + wave * 16 + srow) * lda + sg * 8;
    const ushort_t* aptr1 = A + (size_t)(m0 + 64 + wave * 16 + srow) * lda + sg * 8;
    const ushort_t* bptr0 = W + (size_t)(n0 + wave * 16 + srow) * ldw + sg * 8;
    const ushort_t* bptr1 = W + (size_t)(n0 + 64 + wave * 16 + srow) * ldw + sg * 8;

    auto As = [&](int buf, int kk, int row) -> ushort_t* {
        return Asp + (size_t)((buf * 2 + kk) * BM + row) * 32;
    };
    auto Bs = [&](int buf, int kk, int row) -> ushort_t* {
        return Bsp + (size_t)((buf * 2 + kk) * BN + row) * 32;
    };

    gll16(aptr0,      As(0, 0, wave * 16));
    gll16(aptr0 + 32, As(0, 1, wave * 16));
    if (BM == 128) {
        gll16(aptr1,      As(0, 0, 64 + wave * 16));
        gll16(aptr1 + 32, As(0, 1, 64 + wave * 16));
    }
    gll16(bptr0,      Bs(0, 0, wave * 16));
    gll16(bptr0 + 32, Bs(0, 1, wave * 16));
    if (BN == 128) {
        gll16(bptr1,      Bs(0, 0, 64 + wave * 16));
        gll16(bptr1 + 32, Bs(0, 1, 64 + wave * 16));
    }

    const int ca = ((quad + (l16 >> 1)) & 3) * 8;
    int cur = 0;
    for (int k0 = 0; k0 < K; k0 += 64) {
        __syncthreads();
        if (k0 + 64 < K) {
            const int nb = cur ^ 1, ko = k0 + 64;
            gll16(aptr0 + ko,      As(nb, 0, wave * 16));
            gll16(aptr0 + ko + 32, As(nb, 1, wave * 16));
            if (BM == 128) {
                gll16(aptr1 + ko,      As(nb, 0, 64 + wave * 16));
                gll16(aptr1 + ko + 32, As(nb, 1, 64 + wave * 16));
            }
            gll16(bptr0 + ko,      Bs(nb, 0, wave * 16));
            gll16(bptr0 + ko + 32, Bs(nb, 1, wave * 16));
            if (BN == 128) {
                gll16(bptr1 + ko,      Bs(nb, 0, 64 + wave * 16));
                gll16(bptr1 + ko + 32, Bs(nb, 1, 64 + wave * 16));
            }
        }
#pragma unroll
        for (int kk = 0; kk < 2; ++kk) {
            short8 af[MI], bfr[NI];
#pragma unroll
            for (int mi = 0; mi < MI; ++mi)
                af[mi] = *(const short8*)(As(cur, kk, wm + mi * 16 + l16) + ca);
#pragma unroll
            for (int ni = 0; ni < NI; ++ni)
                bfr[ni] = *(const short8*)(Bs(cur, kk, wn + ni * 16 + l16) + ca);
#pragma unroll
            for (int mi = 0; mi < MI; ++mi)
#pragma unroll
                for (int ni = 0; ni < NI; ++ni)
                    acc[mi][ni] = __builtin_amdgcn_mfma_f32_16x16x32_bf16(
                        af[mi], bfr[ni], acc[mi][ni], 0, 0, 0);
        }
        cur ^= 1;
    }

#pragma unroll
    for (int ni = 0; ni < NI; ++ni) {
        const int col = n0 + wn + ni * 16 + l16;
        const float bv = (KSPLIT && second) ? 0.f : bias[col];
#pragma unroll
        for (int mi = 0; mi < MI; ++mi)
#pragma unroll
            for (int r = 0; r < 4; ++r) {
                const int row = m0 + wm + mi * 16 + quad * 4 + r;
                float v = acc[mi][ni][r] + bv;
                if (RELU) v = fmaxf(v, 0.f);
                store_out(&Cw[(size_t)row * ldc + col], v);
            }
    }
}

// ---------------------------------------------------------------------------
// Merged dispatch: blocks 0..1023 = self o-proj (64x64, K-split x2, reads qkv
// cols 0..512, writes pA/pB); blocks 1024..1535 = cross K/V projection
// (64x128, by 4..11, reads mb, writes qkv cols 512..1536). Regions disjoint,
// no sync needed. Removes the cross-KV work from the post-LN1 critical path.
// ---------------------------------------------------------------------------
__global__ __launch_bounds__(256, 3) void oproj_ckv(
    const ushort_t* __restrict__ qkv_in, const ushort_t* __restrict__ sWo_t,
    const float* __restrict__ bias_o,
    ushort_t* __restrict__ pA, ushort_t* __restrict__ pB,
    const ushort_t* __restrict__ mb, const ushort_t* __restrict__ cWqkv_t,
    const float* __restrict__ bias_c, ushort_t* __restrict__ qkv_out)
{
    __shared__ ushort_t pool[24576];   // 48 KB (max of both paths)
    const int t = blockIdx.x;
    if (t < 1024) {
        gemm_body<ushort_t, false, 64, 64, true>(pool, t & 63, (t >> 6) & 7, t >> 9,
            qkv_in, qkv_in, 0, 1536, sWo_t, 512, bias_o, pA, 512, 256, pB);
    } else {
        const int t2 = t - 1024;
        gemm_body<ushort_t, false, 64, 128, false>(pool, t2 & 63, 4 + (t2 >> 6), 0,
            mb, mb, 4, 512, cWqkv_t, 512, bias_c, qkv_out, 1536, 512,
            (ushort_t*)nullptr);
    }
}

// ---------------------------------------------------------------------------
// Standalone GEMM (unchanged from round 7).
// ---------------------------------------------------------------------------
template<typename OutT, bool RELU, int BM, int BN, bool KSPLIT>
__global__ __launch_bounds__(256, (BM == 64) ? 3 : 2) void gemm_tn(
    const ushort_t* __restrict__ A1, const ushort_t* __restrict__ A2,
    int ySplit, int lda,
    const ushort_t* __restrict__ Wt, int ldw,
    const float* __restrict__ bias,
    OutT* __restrict__ C, int ldc, int K,
    OutT* __restrict__ C2)
{
    constexpr int WC = (BM == 64 && BN == 128) ? 4 : 2;
    constexpr int WR = 4 / WC;
    constexpr int MI = BM / (WR * 16);
    constexpr int NI = BN / (WC * 16);
    __shared__ ushort_t As[2][2][BM][32];
    __shared__ ushort_t Bs[2][2][BN][32];
    const int tid = threadIdx.x;
    const int wave = tid >> 6, lane = tid & 63;
    const int quad = lane >> 4, l16 = lane & 15;
    const int m0 = blockIdx.x * BM, n0 = blockIdx.y * BN;
    const int wm = (wave / WC) * (BM / WR);
    const int wn = (wave % WC) * (BN / WC);
    const ushort_t* A = (((int)blockIdx.y) < ySplit) ? A1 : A2;
    const ushort_t* W = Wt;
    OutT* Cw = C;
    bool second = false;
    if (KSPLIT && blockIdx.z) { A += K; W += K; Cw = C2; second = true; }

    float4v acc[MI][NI];
#pragma unroll
    for (int mi = 0; mi < MI; ++mi)
#pragma unroll
        for (int ni = 0; ni < NI; ++ni) {
            acc[mi][ni][0] = 0.f; acc[mi][ni][1] = 0.f;
            acc[mi][ni][2] = 0.f; acc[mi][ni][3] = 0.f;
        }

    const int srow = lane >> 2;
    const int scc  = lane & 3;
    const int sg   = (scc - (lane >> 3)) & 3;
    const ushort_t* aptr0 = A  + (size_t)(m0 + wave * 16 + srow) * lda + sg * 8;
    const ushort_t* aptr1 = A  + (size_t)(m0 + 64 + wave * 16 + srow) * lda + sg * 8;
    const ushort_t* bptr0 = W + (size_t)(n0 + wave * 16 + srow) * ldw + sg * 8;
    const ushort_t* bptr1 = W + (size_t)(n0 + 64 + wave * 16 + srow) * ldw + sg * 8;

    gll16(aptr0,      &As[0][0][wave * 16][0]);
    gll16(aptr0 + 32, &As[0][1][wave * 16][0]);
    if (BM == 128) {
        gll16(aptr1,      &As[0][0][64 + wave * 16][0]);
        gll16(aptr1 + 32, &As[0][1][64 + wave * 16][0]);
    }
    gll16(bptr0,      &Bs[0][0][wave * 16][0]);
    gll16(bptr0 + 32, &Bs[0][1][wave * 16][0]);
    if (BN == 128) {
        gll16(bptr1,      &Bs[0][0][64 + wave * 16][0]);
        gll16(bptr1 + 32, &Bs[0][1][64 + wave * 16][0]);
    }

    const int ca = ((quad + (l16 >> 1)) & 3) * 8;
    int cur = 0;
    for (int k0 = 0; k0 < K; k0 += 64) {
        __syncthreads();
        if (k0 + 64 < K) {
            const int nb = cur ^ 1, ko = k0 + 64;
            gll16(aptr0 + ko,      &As[nb][0][wave * 16][0]);
            gll16(aptr0 + ko + 32, &As[nb][1][wave * 16][0]);
            if (BM == 128) {
                gll16(aptr1 + ko,      &As[nb][0][64 + wave * 16][0]);
                gll16(aptr1 + ko + 32, &As[nb][1][64 + wave * 16][0]);
            }
            gll16(bptr0 + ko,      &Bs[nb][0][wave * 16][0]);
            gll16(bptr0 + ko + 32, &Bs[nb][1][wave * 16][0]);
            if (BN == 128) {
                gll16(bptr1 + ko,      &Bs[nb][0][64 + wave * 16][0]);
                gll16(bptr1 + ko + 32, &Bs[nb][1][64 + wave * 16][0]);
            }
        }
#pragma unroll
        for (int kk = 0; kk < 2; ++kk) {
            short8 af[MI], bfr[NI];
#pragma unroll
            for (int mi = 0; mi < MI; ++mi)
                af[mi] = *(const short8*)(&As[cur][kk][wm + mi * 16 + l16][ca]);
#pragma unroll
            for (int ni = 0; ni < NI; ++ni)
                bfr[ni] = *(const short8*)(&Bs[cur][kk][wn + ni * 16 + l16][ca]);
#pragma unroll
            for (int mi = 0; mi < MI; ++mi)
#pragma unroll
                for (int ni = 0; ni < NI; ++ni)
                    acc[mi][ni] = __builtin_amdgcn_mfma_f32_16x16x32_bf16(
                        af[mi], bfr[ni], acc[mi][ni], 0, 0, 0);
        }
        cur ^= 1;
    }

#pragma unroll
    for (int ni = 0; ni < NI; ++ni) {
        const int col = n0 + wn + ni * 16 + l16;
        const float bv = (KSPLIT && second) ? 0.f : bias[col];
#pragma unroll
        for (int mi = 0; mi < MI; ++mi)
#pragma unroll
            for (int r = 0; r < 4; ++r) {
                const int row = m0 + wm + mi * 16 + quad * 4 + r;
                float v = acc[mi][ni][r] + bv;
                if (RELU) v = fmaxf(v, 0.f);
                store_out(&Cw[(size_t)row * ldc + col], v);
            }
    }
}

// ---------------------------------------------------------------------------
// Flash attention (MFMA), 512 threads / 8 waves, intra-block split-S.
// (unchanged from round 7)
// ---------------------------------------------------------------------------
__global__ __launch_bounds__(512) void attn_mfma(ushort_t* __restrict__ QKV)
{
    const int S = 1536;
    __shared__ ushort_t PsA[64][72];
    __shared__ ushort_t PsB[64][72];
    __shared__ ushort_t Ks[2][64][72];
    __shared__ ushort_t Vt[2][64][72];

    const int tid  = threadIdx.x;
    const int w    = tid >> 6;
    const int g    = w >> 2;
    const int wq   = w & 3;
    const int lane = tid & 63;
    const int quad = lane >> 4, l16 = lane & 15;
    const int ht   = tid & 255;
    const int qt = blockIdx.x, bh = blockIdx.y;
    const int b = bh >> 3, h = bh & 7;
    const size_t rowQ = (size_t)b * 1024 + qt * 64;
    const size_t kv0  = (size_t)b * 1024;

    const int kr = ht >> 2, kc = (ht & 3) * 16;
    const int sp = ht >> 3, dc = (ht & 7) * 8;
    const int vr0 = sp * 2;
    const int vrg = vr0 >> 3, vrof = vr0 & 7;

    {
        const int r = tid >> 3, c = (tid & 7) * 8;
        *(uint4*)(&PsA[r][c]) = *(const uint4*)(QKV + (rowQ + r) * S + h * 64 + c);
    }
    __syncthreads();
    short8 qf[2];
    qf[0] = *(const short8*)(&PsA[wq * 16 + l16][quad * 8]);
    qf[1] = *(const short8*)(&PsA[wq * 16 + l16][32 + quad * 8]);
    ushort_t (* __restrict__ Ps)[72] = g ? PsB : PsA;

    const float CEXP = 0.125f * 1.44269504f;
    const float MREF = 16.0f * CEXP;
    float lsum[4];
    float4v oacc[4];
#pragma unroll
    for (int r = 0; r < 4; ++r) lsum[r] = 0.f;
#pragma unroll
    for (int n = 0; n < 4; ++n) { oacc[n][0]=0.f; oacc[n][1]=0.f; oacc[n][2]=0.f; oacc[n][3]=0.f; }

    uint4 kA, kB, vA, vB;
    {
        const size_t sr = kv0 + g * 64;
        const ushort_t* ksrc = QKV + (sr + kr) * S + 512 + h * 64 + kc;
        kA = *(const uint4*)(ksrc);
        kB = *(const uint4*)(ksrc + 8);
        const ushort_t* vsrc = QKV + (sr + vr0) * S + 1024 + h * 64 + dc;
        vA = *(const uint4*)(vsrc);
        vB = *(const uint4*)(vsrc + S);
    }

    for (int it = 0; it < 8; ++it) {
        __syncthreads();
        *(uint4*)(&Ks[g][kr][kc])     = kA;
        *(uint4*)(&Ks[g][kr][kc + 8]) = kB;
        {
            const ushort_t* ae = (const ushort_t*)&vA;
            const ushort_t* be = (const ushort_t*)&vB;
#pragma unroll
            for (int j = 0; j < 8; ++j) {
                const int d = dc + j;
                const int cc = (vrg ^ (d >> 4)) & 7;
                *(unsigned int*)(&Vt[g][d][cc * 8 + vrof]) =
                    (unsigned int)ae[j] | ((unsigned int)be[j] << 16);
            }
        }
        __syncthreads();
        if (it < 7) {
            const size_t sr = kv0 + (it + 1) * 128 + g * 64;
            const ushort_t* ksrc = QKV + (sr + kr) * S + 512 + h * 64 + kc;
            kA = *(const uint4*)(ksrc);
            kB = *(const uint4*)(ksrc + 8);
            const ushort_t* vsrc = QKV + (sr + vr0) * S + 1024 + h * 64 + dc;
            vA = *(const uint4*)(vsrc);
            vB = *(const uint4*)(vsrc + S);
        }

        float4v sc[4];
#pragma unroll
        for (int sb = 0; sb < 4; ++sb) {
            float4v z; z[0]=0.f; z[1]=0.f; z[2]=0.f; z[3]=0.f;
            short8 kf0 = *(const short8*)(&Ks[g][sb * 16 + l16][quad * 8]);
            short8 kf1 = *(const short8*)(&Ks[g][sb * 16 + l16][32 + quad * 8]);
            z = __builtin_amdgcn_mfma_f32_16x16x32_bf16(qf[0], kf0, z, 0, 0, 0);
            z = __builtin_amdgcn_mfma_f32_16x16x32_bf16(qf[1], kf1, z, 0, 0, 0);
            sc[sb] = z;
        }

#pragma unroll
        for (int sb = 0; sb < 4; ++sb)
#pragma unroll
            for (int r = 0; r < 4; ++r) {
                float p = exp2f(fmaf(sc[sb][r], CEXP, -MREF));
                lsum[r] += p;
                Ps[wq * 16 + quad * 4 + r][sb * 16 + l16] = f2bf(p);
            }

        short8 pf[2];
        pf[0] = *(const short8*)(&Ps[wq * 16 + l16][quad * 8]);
        pf[1] = *(const short8*)(&Ps[wq * 16 + l16][32 + quad * 8]);
#pragma unroll
        for (int n = 0; n < 4; ++n) {
#pragma unroll
            for (int kc2 = 0; kc2 < 2; ++kc2) {
                const int cc = ((kc2 * 4 + quad) ^ n) & 7;
                short8 vf = *(const short8*)(&Vt[g][n * 16 + l16][cc * 8]);
                oacc[n] = __builtin_amdgcn_mfma_f32_16x16x32_bf16(pf[kc2], vf, oacc[n], 0, 0, 0);
            }
        }
    }

#pragma unroll
    for (int msk = 1; msk < 16; msk <<= 1)
#pragma unroll
        for (int r = 0; r < 4; ++r) lsum[r] += __shfl_xor(lsum[r], msk);

    float* exch = (float*)&Ks[0][0][0];
    float* exl  = (float*)&Vt[0][0][0];
    __syncthreads();
    if (g == 1) {
#pragma unroll
        for (int n = 0; n < 4; ++n)
#pragma unroll
            for (int r = 0; r < 4; ++r)
                exch[((wq * 4 + n) * 4 + r) * 64 + lane] = oacc[n][r];
        if (l16 == 0)
#pragma unroll
            for (int r = 0; r < 4; ++r) exl[wq * 16 + quad * 4 + r] = lsum[r];
    }
    __syncthreads();
    if (g == 0) {
#pragma unroll
        for (int r = 0; r < 4; ++r) lsum[r] += exl[wq * 16 + quad * 4 + r];
        float inv[4];
#pragma unroll
        for (int r = 0; r < 4; ++r) inv[r] = 1.f / lsum[r];
#pragma unroll
        for (int n = 0; n < 4; ++n)
#pragma unroll
            for (int r = 0; r < 4; ++r) {
                float o = oacc[n][r] + exch[((wq * 4 + n) * 4 + r) * 64 + lane];
                const size_t row = rowQ + wq * 16 + quad * 4 + r;
                QKV[row * S + h * 64 + n * 16 + l16] = f2bf(o * inv[r]);
            }
    }
}

// ---------------------------------------------------------------------------
// LayerNorm over E=512. Delta = sum of TWO bf16 partial buffers.
// (unchanged from round 7)
// ---------------------------------------------------------------------------
template<bool RES_EXT, bool OUT_EXT>
__global__ __launch_bounds__(256) void ln_kernel(
    const void* __restrict__ res,
    const ushort_t* __restrict__ d1, const ushort_t* __restrict__ d2,
    const void* __restrict__ g, const void* __restrict__ be,
    void* __restrict__ out, int mode, const int* __restrict__ dflag)
{
    const int E = 512;
    const bool extf32 = is_f32(mode, dflag);
    const int row = blockIdx.x, tid = threadIdx.x;
    const int wave = tid >> 6, lane = tid & 63;
    const size_t base = (size_t)row * E;
    const int i0 = tid, i1 = tid + 256;

    float r0, r1;
    if (RES_EXT && extf32) {
        r0 = ((const float*)res)[base + i0];
        r1 = ((const float*)res)[base + i1];
    } else {
        r0 = bf2f(((const ushort_t*)res)[base + i0]);
        r1 = bf2f(((const ushort_t*)res)[base + i1]);
    }
    float d0v = bf2f(d1[base + i0]) + bf2f(d2[base + i0]);
    float d1v = bf2f(d1[base + i1]) + bf2f(d2[base + i1]);
    float x0 = r0 + d0v, x1 = r1 + d1v;

    __shared__ float red8[8];
    float s = x0 + x1;
#pragma unroll
    for (int m = 1; m < 64; m <<= 1) s += __shfl_xor(s, m);
    if (lane == 0) red8[wave] = s;
    __syncthreads();
    float mean = (red8[0] + red8[1] + red8[2] + red8[3]) * (1.0f / 512.0f);
    float dd0 = x0 - mean, dd1 = x1 - mean;
    float v = dd0 * dd0 + dd1 * dd1;
#pragma unroll
    for (int m = 1; m < 64; m <<= 1) v += __shfl_xor(v, m);
    if (lane == 0) red8[4 + wave] = v;
    __syncthreads();
    float rstd = rsqrtf((red8[4] + red8[5] + red8[6] + red8[7]) * (1.0f / 512.0f) + 1e-5f);

    float g0, g1v, b0, b1;
    if (extf32) {
        g0 = ((const float*)g)[i0];  g1v = ((const float*)g)[i1];
        b0 = ((const float*)be)[i0]; b1  = ((const float*)be)[i1];
    } else {
        g0 = bf2f(((const ushort_t*)g)[i0]);  g1v = bf2f(((const ushort_t*)g)[i1]);
        b0 = bf2f(((const ushort_t*)be)[i0]); b1  = bf2f(((const ushort_t*)be)[i1]);
    }
    float y0 = dd0 * rstd * g0 + b0;
    float y1 = dd1 * rstd * g1v + b1;
    if (OUT_EXT && extf32) {
        ((float*)out)[base + i0] = y0; ((float*)out)[base + i1] = y1;
    } else {
        ((ushort_t*)out)[base + i0] = f2bf(y0);
        ((ushort_t*)out)[base + i1] = f2bf(y1);
    }
}

// ---------------------------------------------------------------------------
// Workspace (~36.3 MiB), liveness-checked layout (unchanged).
// ---------------------------------------------------------------------------

extern "C" void kernel_launch(void* const* d_in, const int* in_sizes, int n_in,
                              void* d_out, int out_size, void* d_ws, size_t ws_size,
                              hipStream_t stream) {
    const void* tgt = d_in[0];
    const void* mem = d_in[1];
    const void* sWq = d_in[2];  const void* sWk = d_in[3];
    const void* sWv = d_in[4];  const void* sWo = d_in[5];
    const void* cWq = d_in[6];  const void* cWk = d_in[7];
    const void* cWv = d_in[8];  const void* cWo = d_in[9];
    const void* sbq = d_in[10]; const void* sbk = d_in[11];
    const void* sbv = d_in[12]; const void* sbo = d_in[13];
    const void* cbq = d_in[14]; const void* cbk = d_in[15];
    const void* cbv = d_in[16]; const void* cbo = d_in[17];
    const void* fW1 = d_in[18]; const void* fb1 = d_in[19];
    const void* fW2 = d_in[20]; const void* fb2 = d_in[21];
    const void* g1  = d_in[22]; const void* g2  = d_in[23];
    const void* g3  = d_in[24];
    const void* be1 = d_in[25]; const void* be2 = d_in[26];
    const void* be3 = d_in[27];

    char* ws = (char*)d_ws;
    const size_t MB = 1048576;
    ushort_t* qkv = (ushort_t*)(ws + 0 * MB);
    ushort_t* hb  = (ushort_t*)(ws + 0 * MB);    // FFN hidden [4096][2048]
    ushort_t* pA  = (ushort_t*)(ws + 12 * MB);   // o-proj partial A
    ushort_t* xb  = (ushort_t*)(ws + 16 * MB);
    ushort_t* tb  = (ushort_t*)(ws + 20 * MB);
    ushort_t* mb  = (ushort_t*)(ws + 24 * MB);
    ushort_t* pB  = (ushort_t*)(ws + 20 * MB);   // o-proj partial B (tb region)
    ushort_t* ofA = (ushort_t*)(ws + 20 * MB);   // FFN2 partial A
    ushort_t* ofB = (ushort_t*)(ws + 24 * MB);   // FFN2 partial B
    ushort_t* wb  = (ushort_t*)(ws + 28 * MB);
    float*    pb  = (float*)   (ws + 36 * MB);
    int*   dflag  = (int*)     (ws + 36 * MB + 262144);

    const ushort_t* sWqkv_t = wb + 0;
    const ushort_t* sWo_t   = wb + 786432;
    const ushort_t* cWqkv_t = wb + 1048576;
    const ushort_t* cWo_t   = wb + 1835008;
    const ushort_t* fW1_t   = wb + 2097152;
    const ushort_t* fW2_t   = wb + 3145728;

    dim3 blk(256);

    int mode;
    if (in_sizes[0] == 4 * 1024 * 512 * 4)      mode = 0;   // f32
    else if (in_sizes[0] == 4 * 1024 * 512 * 2) mode = 1;   // bf16
    else                                        mode = 2;   // detect on device
    if (mode == 2)
        detect_dtype<<<dim3(1), blk, 0, stream>>>((const ushort_t*)tgt, dflag);

    prep_all<<<dim3(3098), blk, 0, stream>>>(
        sWq, sWk, sWv, sWo, cWq, cWk, cWv, cWo, fW1, fW2,
        tgt, mem, sbq, sbk, sbv, sbo, cbq, cbk, cbv, cbo, fb1, fb2,
        wb, tb, mb, pb, mode, dflag);

    dim3 gattn(16, 32);
    dim3 blk512(512);

    // ---- self-attention ----
    gemm_tn<ushort_t, false, 64, 128, false><<<dim3(64, 12), blk, 0, stream>>>(
        tb, tb, 0, 512, sWqkv_t, 512, pb + 0, qkv, 1536, 512, (ushort_t*)nullptr);
    attn_mfma<<<gattn, blk512, 0, stream>>>(qkv);
    // merged: self o-proj (1024 blocks) + cross K/V projection (512 blocks)
    oproj_ckv<<<dim3(1536), blk, 0, stream>>>(
        qkv, sWo_t, pb + 1536, pA, pB, mb, cWqkv_t, pb + 2048, qkv);
    ln_kernel<true, false><<<dim3(4096), blk, 0, stream>>>(
        tgt, pA, pB, g1, be1, xb, mode, dflag);

    // ---- cross-attention (Q projection only; K/V already in qkv) ----
    gemm_tn<ushort_t, false, 64, 128, false><<<dim3(64, 4), blk, 0, stream>>>(
        xb, mb, 4, 512, cWqkv_t, 512, pb + 2048, qkv, 1536, 512, (ushort_t*)nullptr);
    attn_mfma<<<gattn, blk512, 0, stream>>>(qkv);
    gemm_tn<ushort_t, false, 64, 64, true><<<dim3(64, 8, 2), blk, 0, stream>>>(
        qkv, qkv, 0, 1536, cWo_t, 512, pb + 3584, pA, 512, 256, pB);
    ln_kernel<false, false><<<dim3(4096), blk, 0, stream>>>(
        xb, pA, pB, g2, be2, xb, mode, dflag);

    // ---- FFN ----
    gemm_tn<ushort_t, true, 128, 128, false><<<dim3(32, 16), blk, 0, stream>>>(
        xb, xb, 0, 512, fW1_t, 512, pb + 4096, hb, 2048, 512, (ushort_t*)nullptr);
    gemm_tn<ushort_t, false, 64, 64, true><<<dim3(64, 8, 2), blk, 0, stream>>>(
        hb, hb, 0, 2048, fW2_t, 2048, pb + 6144, ofA, 512, 1024, ofB);
    ln_kernel<false, true><<<dim3(4096), blk, 0, stream>>>(
        xb, ofA, ofB, g3, be3, d_out, mode, dflag);
}

// Round 10
// 263.524 us; speedup vs baseline: 1.0326x; 1.0326x over previous
//
#include <hip/hip_runtime.h>

typedef unsigned short ushort_t;
typedef short short8 __attribute__((ext_vector_type(8)));
typedef float float4v __attribute__((ext_vector_type(4)));

__device__ __forceinline__ float bf2f(ushort_t u) {
    union { unsigned int i; float f; } x; x.i = ((unsigned int)u) << 16; return x.f;
}
__device__ __forceinline__ ushort_t f2bf(float f) {
    unsigned int u = __float_as_uint(f);
    unsigned int r = (u + 0x7FFFu + ((u >> 16) & 1u)) >> 16;
    return (ushort_t)r;
}
__device__ __forceinline__ void store_out(float* p, float v) { *p = v; }
__device__ __forceinline__ void store_out(ushort_t* p, float v) { *p = f2bf(v); }

// async global->LDS 16B/lane; lds ptr must be wave-uniform base (lane*16 auto)
__device__ __forceinline__ void gll16(const ushort_t* g, ushort_t* l) {
    __builtin_amdgcn_global_load_lds(
        (const __attribute__((address_space(1))) void*)g,
        (__attribute__((address_space(3))) void*)l, 16, 0, 0);
}

// ---------------------------------------------------------------------------
// Fallback input-dtype detection (only launched when in_sizes is ambiguous).
// ---------------------------------------------------------------------------
__global__ void detect_dtype(const ushort_t* __restrict__ tgt, int* __restrict__ flag) {
    __shared__ int red[256];
    const int tid = threadIdx.x;
    int p = 0;
    for (int i = tid; i < 512; i += 256) {
        ushort_t u = tgt[i];
        int e = (u >> 7) & 0xFF;
        if (u == 0 || (e >= 100 && e <= 140)) ++p;
    }
    red[tid] = p; __syncthreads();
    for (int off = 128; off > 0; off >>= 1) {
        if (tid < off) red[tid] += red[tid + off];
        __syncthreads();
    }
    if (tid == 0) flag[0] = (red[0] >= 480) ? 1 : 0;
}

__device__ __forceinline__ bool is_f32(int mode, const int* dflag) {
    return (mode == 2) ? (dflag[0] == 0) : (mode == 0);
}

// ---------------------------------------------------------------------------
// Unified prep, exact flat grid of 3098 blocks:
//   id    0..511 : 8x 512x512 weight transposes (64 tiles each)
//   id  512..767 : fW1 512x2048 transpose
//   id  768..1023: fW2 2048x512 transpose
//   id 1024..2047: tgt -> bf16 ; id 2048..3071: mem -> bf16
//   id 3072..3097: biases -> packed f32 [6656]
// ---------------------------------------------------------------------------
__global__ __launch_bounds__(256) void prep_all(
    const void* sWq, const void* sWk, const void* sWv, const void* sWo,
    const void* cWq, const void* cWk, const void* cWv, const void* cWo,
    const void* fW1, const void* fW2,
    const void* tgt, const void* mem,
    const void* sbq, const void* sbk, const void* sbv, const void* sbo,
    const void* cbq, const void* cbk, const void* cbv, const void* cbo,
    const void* fb1, const void* fb2,
    ushort_t* __restrict__ wb, ushort_t* __restrict__ tb, ushort_t* __restrict__ mb,
    float* __restrict__ pb, int mode, const int* __restrict__ dflag)
{
    const bool f32 = is_f32(mode, dflag);
    const int tid = threadIdx.x;
    const int id = blockIdx.x;

    if (id < 1024) {
        int z, kt, nt;
        if (id < 512)      { z = id >> 6;  int t = id & 63;  kt = t >> 3; nt = t & 7;  }
        else if (id < 768) { z = 8;        int t = id - 512; kt = t >> 5; nt = t & 31; }
        else               { z = 9;        int t = id - 768; kt = t >> 3; nt = t & 7;  }
        const void* src; ushort_t* dst; int Kd, Nd;
        switch (z) {
            case 0: src = sWq; dst = wb + 0;       Kd = 512;  Nd = 512;  break;
            case 1: src = sWk; dst = wb + 262144;  Kd = 512;  Nd = 512;  break;
            case 2: src = sWv; dst = wb + 524288;  Kd = 512;  Nd = 512;  break;
            case 3: src = sWo; dst = wb + 786432;  Kd = 512;  Nd = 512;  break;
            case 4: src = cWq; dst = wb + 1048576; Kd = 512;  Nd = 512;  break;
            case 5: src = cWk; dst = wb + 1310720; Kd = 512;  Nd = 512;  break;
            case 6: src = cWv; dst = wb + 1572864; Kd = 512;  Nd = 512;  break;
            case 7: src = cWo; dst = wb + 1835008; Kd = 512;  Nd = 512;  break;
            case 8: src = fW1; dst = wb + 2097152; Kd = 512;  Nd = 2048; break;
            default:src = fW2; dst = wb + 3145728; Kd = 2048; Nd = 512;  break;
        }
        const int k0 = kt * 64, n0 = nt * 64;
        __shared__ ushort_t T[64][65];
#pragma unroll
        for (int i = 0; i < 16; ++i) {
            int j = i * 256 + tid;
            int r = j >> 6, c = j & 63;
            float v = f32 ? ((const float*)src)[(size_t)(k0 + r) * Nd + n0 + c]
                          : bf2f(((const ushort_t*)src)[(size_t)(k0 + r) * Nd + n0 + c]);
            T[r][c] = f2bf(v);
        }
        __syncthreads();
#pragma unroll
        for (int i = 0; i < 16; ++i) {
            int j = i * 256 + tid;
            int n = j >> 6, k = j & 63;
            dst[(size_t)(n0 + n) * Kd + k0 + k] = T[k][n];
        }
        return;
    }

    if (id < 3072) {
        const int bid0 = id - 1024;
        const void* src = (bid0 < 1024) ? tgt : mem;
        ushort_t* dst = (bid0 < 1024) ? tb : mb;
        const int bid = bid0 & 1023;
        const int i = (bid * 256 + tid) * 8;
        if (f32) {
            float4 v0 = *(const float4*)((const float*)src + i);
            float4 v1 = *(const float4*)((const float*)src + i + 4);
            ushort_t o[8] = { f2bf(v0.x), f2bf(v0.y), f2bf(v0.z), f2bf(v0.w),
                              f2bf(v1.x), f2bf(v1.y), f2bf(v1.z), f2bf(v1.w) };
            *(uint4*)(dst + i) = *(const uint4*)o;
        } else {
            *(uint4*)(dst + i) = *(const uint4*)((const ushort_t*)src + i);
        }
        return;
    }

    {
        const int i = (id - 3072) * 256 + tid;
        if (i >= 6656) return;
        const void* src; int off;
        if      (i < 512)  { src = sbq; off = i; }
        else if (i < 1024) { src = sbk; off = i - 512; }
        else if (i < 1536) { src = sbv; off = i - 1024; }
        else if (i < 2048) { src = sbo; off = i - 1536; }
        else if (i < 2560) { src = cbq; off = i - 2048; }
        else if (i < 3072) { src = cbk; off = i - 2560; }
        else if (i < 3584) { src = cbv; off = i - 3072; }
        else if (i < 4096) { src = cbo; off = i - 3584; }
        else if (i < 6144) { src = fb1; off = i - 4096; }
        else               { src = fb2; off = i - 6144; }
        pb[i] = f32 ? ((const float*)src)[off] : bf2f(((const ushort_t*)src)[off]);
    }
}

// ---------------------------------------------------------------------------
// GEMM, BK=64 as two interleaved 32-col panels. Tile shape (BM,BN) templated:
//   128x128: 4 waves 2x2, 64x64/wave, LDS 64KB (2 blk/CU)
//   64x128 : 4 waves 1x4, 64x32/wave, LDS 48KB (3 blk/CU) - QKV grid 768
//   64x64  : 4 waves 2x2, 32x32/wave, LDS 32KB (4 blk/CU) - oproj/FFN2 grid 1024
// Staging swizzle, barrier structure, and accumulation order unchanged.
// KSPLIT: blockIdx.z selects K-half; z=0 -> C (+bias), z=1 -> C2 (no bias).
// ---------------------------------------------------------------------------
template<typename OutT, bool RELU, int BM, int BN, bool KSPLIT>
__global__ __launch_bounds__(256, (BM == 64) ? 3 : 2) void gemm_tn(
    const ushort_t* __restrict__ A1, const ushort_t* __restrict__ A2,
    int ySplit, int lda,
    const ushort_t* __restrict__ Wt, int ldw,
    const float* __restrict__ bias,
    OutT* __restrict__ C, int ldc, int K,
    OutT* __restrict__ C2)
{
    constexpr int WC = (BM == 64 && BN == 128) ? 4 : 2;   // wave cols
    constexpr int WR = 4 / WC;                            // wave rows
    constexpr int MI = BM / (WR * 16);
    constexpr int NI = BN / (WC * 16);
    __shared__ ushort_t As[2][2][BM][32];
    __shared__ ushort_t Bs[2][2][BN][32];
    const int tid = threadIdx.x;
    const int wave = tid >> 6, lane = tid & 63;
    const int quad = lane >> 4, l16 = lane & 15;
    const int m0 = blockIdx.x * BM, n0 = blockIdx.y * BN;
    const int wm = (wave / WC) * (BM / WR);
    const int wn = (wave % WC) * (BN / WC);
    const ushort_t* A = (((int)blockIdx.y) < ySplit) ? A1 : A2;
    const ushort_t* W = Wt;
    OutT* Cw = C;
    bool second = false;
    if (KSPLIT && blockIdx.z) { A += K; W += K; Cw = C2; second = true; }

    float4v acc[MI][NI];
#pragma unroll
    for (int mi = 0; mi < MI; ++mi)
#pragma unroll
        for (int ni = 0; ni < NI; ++ni) {
            acc[mi][ni][0] = 0.f; acc[mi][ni][1] = 0.f;
            acc[mi][ni][2] = 0.f; acc[mi][ni][3] = 0.f;
        }

    const int srow = lane >> 2;
    const int scc  = lane & 3;
    const int sg   = (scc - (lane >> 3)) & 3;
    const ushort_t* aptr0 = A  + (size_t)(m0 + wave * 16 + srow) * lda + sg * 8;
    const ushort_t* aptr1 = A  + (size_t)(m0 + 64 + wave * 16 + srow) * lda + sg * 8;
    const ushort_t* bptr0 = W + (size_t)(n0 + wave * 16 + srow) * ldw + sg * 8;
    const ushort_t* bptr1 = W + (size_t)(n0 + 64 + wave * 16 + srow) * ldw + sg * 8;

    // prologue: stage buffer 0, both panels
    gll16(aptr0,      &As[0][0][wave * 16][0]);
    gll16(aptr0 + 32, &As[0][1][wave * 16][0]);
    if (BM == 128) {
        gll16(aptr1,      &As[0][0][64 + wave * 16][0]);
        gll16(aptr1 + 32, &As[0][1][64 + wave * 16][0]);
    }
    gll16(bptr0,      &Bs[0][0][wave * 16][0]);
    gll16(bptr0 + 32, &Bs[0][1][wave * 16][0]);
    if (BN == 128) {
        gll16(bptr1,      &Bs[0][0][64 + wave * 16][0]);
        gll16(bptr1 + 32, &Bs[0][1][64 + wave * 16][0]);
    }

    const int ca = ((quad + (l16 >> 1)) & 3) * 8;
    int cur = 0;
    for (int k0 = 0; k0 < K; k0 += 64) {
        __syncthreads();
        if (k0 + 64 < K) {
            const int nb = cur ^ 1, ko = k0 + 64;
            gll16(aptr0 + ko,      &As[nb][0][wave * 16][0]);
            gll16(aptr0 + ko + 32, &As[nb][1][wave * 16][0]);
            if (BM == 128) {
                gll16(aptr1 + ko,      &As[nb][0][64 + wave * 16][0]);
                gll16(aptr1 + ko + 32, &As[nb][1][64 + wave * 16][0]);
            }
            gll16(bptr0 + ko,      &Bs[nb][0][wave * 16][0]);
            gll16(bptr0 + ko + 32, &Bs[nb][1][wave * 16][0]);
            if (BN == 128) {
                gll16(bptr1 + ko,      &Bs[nb][0][64 + wave * 16][0]);
                gll16(bptr1 + ko + 32, &Bs[nb][1][64 + wave * 16][0]);
            }
        }
#pragma unroll
        for (int kk = 0; kk < 2; ++kk) {
            short8 af[MI], bfr[NI];
#pragma unroll
            for (int mi = 0; mi < MI; ++mi)
                af[mi] = *(const short8*)(&As[cur][kk][wm + mi * 16 + l16][ca]);
#pragma unroll
            for (int ni = 0; ni < NI; ++ni)
                bfr[ni] = *(const short8*)(&Bs[cur][kk][wn + ni * 16 + l16][ca]);
#pragma unroll
            for (int mi = 0; mi < MI; ++mi)
#pragma unroll
                for (int ni = 0; ni < NI; ++ni)
                    acc[mi][ni] = __builtin_amdgcn_mfma_f32_16x16x32_bf16(
                        af[mi], bfr[ni], acc[mi][ni], 0, 0, 0);
        }
        cur ^= 1;
    }

#pragma unroll
    for (int ni = 0; ni < NI; ++ni) {
        const int col = n0 + wn + ni * 16 + l16;
        const float bv = (KSPLIT && second) ? 0.f : bias[col];
#pragma unroll
        for (int mi = 0; mi < MI; ++mi)
#pragma unroll
            for (int r = 0; r < 4; ++r) {
                const int row = m0 + wm + mi * 16 + quad * 4 + r;
                float v = acc[mi][ni][r] + bv;
                if (RELU) v = fmaxf(v, 0.f);
                store_out(&Cw[(size_t)row * ldc + col], v);
            }
    }
}

// ---------------------------------------------------------------------------
// Flash attention (MFMA), 512 threads / 8 waves, intra-block split-S.
// ---------------------------------------------------------------------------
__global__ __launch_bounds__(512) void attn_mfma(ushort_t* __restrict__ QKV)
{
    const int S = 1536;
    __shared__ ushort_t PsA[64][72];
    __shared__ ushort_t PsB[64][72];
    __shared__ ushort_t Ks[2][64][72];
    __shared__ ushort_t Vt[2][64][72];

    const int tid  = threadIdx.x;
    const int w    = tid >> 6;
    const int g    = w >> 2;
    const int wq   = w & 3;
    const int lane = tid & 63;
    const int quad = lane >> 4, l16 = lane & 15;
    const int ht   = tid & 255;
    const int qt = blockIdx.x, bh = blockIdx.y;
    const int b = bh >> 3, h = bh & 7;
    const size_t rowQ = (size_t)b * 1024 + qt * 64;
    const size_t kv0  = (size_t)b * 1024;

    const int kr = ht >> 2, kc = (ht & 3) * 16;
    const int sp = ht >> 3, dc = (ht & 7) * 8;
    const int vr0 = sp * 2;
    const int vrg = vr0 >> 3, vrof = vr0 & 7;

    {
        const int r = tid >> 3, c = (tid & 7) * 8;
        *(uint4*)(&PsA[r][c]) = *(const uint4*)(QKV + (rowQ + r) * S + h * 64 + c);
    }
    __syncthreads();
    short8 qf[2];
    qf[0] = *(const short8*)(&PsA[wq * 16 + l16][quad * 8]);
    qf[1] = *(const short8*)(&PsA[wq * 16 + l16][32 + quad * 8]);
    ushort_t (* __restrict__ Ps)[72] = g ? PsB : PsA;

    const float CEXP = 0.125f * 1.44269504f;
    const float MREF = 16.0f * CEXP;
    float lsum[4];
    float4v oacc[4];
#pragma unroll
    for (int r = 0; r < 4; ++r) lsum[r] = 0.f;
#pragma unroll
    for (int n = 0; n < 4; ++n) { oacc[n][0]=0.f; oacc[n][1]=0.f; oacc[n][2]=0.f; oacc[n][3]=0.f; }

    uint4 kA, kB, vA, vB;
    {
        const size_t sr = kv0 + g * 64;
        const ushort_t* ksrc = QKV + (sr + kr) * S + 512 + h * 64 + kc;
        kA = *(const uint4*)(ksrc);
        kB = *(const uint4*)(ksrc + 8);
        const ushort_t* vsrc = QKV + (sr + vr0) * S + 1024 + h * 64 + dc;
        vA = *(const uint4*)(vsrc);
        vB = *(const uint4*)(vsrc + S);
    }

    for (int it = 0; it < 8; ++it) {
        __syncthreads();
        *(uint4*)(&Ks[g][kr][kc])     = kA;
        *(uint4*)(&Ks[g][kr][kc + 8]) = kB;
        {
            const ushort_t* ae = (const ushort_t*)&vA;
            const ushort_t* be = (const ushort_t*)&vB;
#pragma unroll
            for (int j = 0; j < 8; ++j) {
                const int d = dc + j;
                const int cc = (vrg ^ (d >> 4)) & 7;
                *(unsigned int*)(&Vt[g][d][cc * 8 + vrof]) =
                    (unsigned int)ae[j] | ((unsigned int)be[j] << 16);
            }
        }
        __syncthreads();
        if (it < 7) {
            const size_t sr = kv0 + (it + 1) * 128 + g * 64;
            const ushort_t* ksrc = QKV + (sr + kr) * S + 512 + h * 64 + kc;
            kA = *(const uint4*)(ksrc);
            kB = *(const uint4*)(ksrc + 8);
            const ushort_t* vsrc = QKV + (sr + vr0) * S + 1024 + h * 64 + dc;
            vA = *(const uint4*)(vsrc);
            vB = *(const uint4*)(vsrc + S);
        }

        float4v sc[4];
#pragma unroll
        for (int sb = 0; sb < 4; ++sb) {
            float4v z; z[0]=0.f; z[1]=0.f; z[2]=0.f; z[3]=0.f;
            short8 kf0 = *(const short8*)(&Ks[g][sb * 16 + l16][quad * 8]);
            short8 kf1 = *(const short8*)(&Ks[g][sb * 16 + l16][32 + quad * 8]);
            z = __builtin_amdgcn_mfma_f32_16x16x32_bf16(qf[0], kf0, z, 0, 0, 0);
            z = __builtin_amdgcn_mfma_f32_16x16x32_bf16(qf[1], kf1, z, 0, 0, 0);
            sc[sb] = z;
        }

#pragma unroll
        for (int sb = 0; sb < 4; ++sb)
#pragma unroll
            for (int r = 0; r < 4; ++r) {
                float p = exp2f(fmaf(sc[sb][r], CEXP, -MREF));
                lsum[r] += p;
                Ps[wq * 16 + quad * 4 + r][sb * 16 + l16] = f2bf(p);
            }

        short8 pf[2];
        pf[0] = *(const short8*)(&Ps[wq * 16 + l16][quad * 8]);
        pf[1] = *(const short8*)(&Ps[wq * 16 + l16][32 + quad * 8]);
#pragma unroll
        for (int n = 0; n < 4; ++n) {
#pragma unroll
            for (int kc2 = 0; kc2 < 2; ++kc2) {
                const int cc = ((kc2 * 4 + quad) ^ n) & 7;
                short8 vf = *(const short8*)(&Vt[g][n * 16 + l16][cc * 8]);
                oacc[n] = __builtin_amdgcn_mfma_f32_16x16x32_bf16(pf[kc2], vf, oacc[n], 0, 0, 0);
            }
        }
    }

#pragma unroll
    for (int msk = 1; msk < 16; msk <<= 1)
#pragma unroll
        for (int r = 0; r < 4; ++r) lsum[r] += __shfl_xor(lsum[r], msk);

    float* exch = (float*)&Ks[0][0][0];
    float* exl  = (float*)&Vt[0][0][0];
    __syncthreads();
    if (g == 1) {
#pragma unroll
        for (int n = 0; n < 4; ++n)
#pragma unroll
            for (int r = 0; r < 4; ++r)
                exch[((wq * 4 + n) * 4 + r) * 64 + lane] = oacc[n][r];
        if (l16 == 0)
#pragma unroll
            for (int r = 0; r < 4; ++r) exl[wq * 16 + quad * 4 + r] = lsum[r];
    }
    __syncthreads();
    if (g == 0) {
#pragma unroll
        for (int r = 0; r < 4; ++r) lsum[r] += exl[wq * 16 + quad * 4 + r];
        float inv[4];
#pragma unroll
        for (int r = 0; r < 4; ++r) inv[r] = 1.f / lsum[r];
#pragma unroll
        for (int n = 0; n < 4; ++n)
#pragma unroll
            for (int r = 0; r < 4; ++r) {
                float o = oacc[n][r] + exch[((wq * 4 + n) * 4 + r) * 64 + lane];
                const size_t row = rowQ + wq * 16 + quad * 4 + r;
                QKV[row * S + h * 64 + n * 16 + l16] = f2bf(o * inv[r]);
            }
    }
}

// ---------------------------------------------------------------------------
// LayerNorm over E=512. Delta = sum of TWO bf16 partial buffers.
// ---------------------------------------------------------------------------
template<bool RES_EXT, bool OUT_EXT>
__global__ __launch_bounds__(256) void ln_kernel(
    const void* __restrict__ res,
    const ushort_t* __restrict__ d1, const ushort_t* __restrict__ d2,
    const void* __restrict__ g, const void* __restrict__ be,
    void* __restrict__ out, int mode, const int* __restrict__ dflag)
{
    const int E = 512;
    const bool extf32 = is_f32(mode, dflag);
    const int row = blockIdx.x, tid = threadIdx.x;
    const int wave = tid >> 6, lane = tid & 63;
    const size_t base = (size_t)row * E;
    const int i0 = tid, i1 = tid + 256;

    float r0, r1;
    if (RES_EXT && extf32) {
        r0 = ((const float*)res)[base + i0];
        r1 = ((const float*)res)[base + i1];
    } else {
        r0 = bf2f(((const ushort_t*)res)[base + i0]);
        r1 = bf2f(((const ushort_t*)res)[base + i1]);
    }
    float d0v = bf2f(d1[base + i0]) + bf2f(d2[base + i0]);
    float d1v = bf2f(d1[base + i1]) + bf2f(d2[base + i1]);
    float x0 = r0 + d0v, x1 = r1 + d1v;

    __shared__ float red8[8];
    float s = x0 + x1;
#pragma unroll
    for (int m = 1; m < 64; m <<= 1) s += __shfl_xor(s, m);
    if (lane == 0) red8[wave] = s;
    __syncthreads();
    float mean = (red8[0] + red8[1] + red8[2] + red8[3]) * (1.0f / 512.0f);
    float dd0 = x0 - mean, dd1 = x1 - mean;
    float v = dd0 * dd0 + dd1 * dd1;
#pragma unroll
    for (int m = 1; m < 64; m <<= 1) v += __shfl_xor(v, m);
    if (lane == 0) red8[4 + wave] = v;
    __syncthreads();
    float rstd = rsqrtf((red8[4] + red8[5] + red8[6] + red8[7]) * (1.0f / 512.0f) + 1e-5f);

    float g0, g1v, b0, b1;
    if (extf32) {
        g0 = ((const float*)g)[i0];  g1v = ((const float*)g)[i1];
        b0 = ((const float*)be)[i0]; b1  = ((const float*)be)[i1];
    } else {
        g0 = bf2f(((const ushort_t*)g)[i0]);  g1v = bf2f(((const ushort_t*)g)[i1]);
        b0 = bf2f(((const ushort_t*)be)[i0]); b1  = bf2f(((const ushort_t*)be)[i1]);
    }
    float y0 = dd0 * rstd * g0 + b0;
    float y1 = dd1 * rstd * g1v + b1;
    if (OUT_EXT && extf32) {
        ((float*)out)[base + i0] = y0; ((float*)out)[base + i1] = y1;
    } else {
        ((ushort_t*)out)[base + i0] = f2bf(y0);
        ((ushort_t*)out)[base + i1] = f2bf(y1);
    }
}

// ---------------------------------------------------------------------------
// Workspace (~36.3 MiB), liveness-checked layout.
// ---------------------------------------------------------------------------

extern "C" void kernel_launch(void* const* d_in, const int* in_sizes, int n_in,
                              void* d_out, int out_size, void* d_ws, size_t ws_size,
                              hipStream_t stream) {
    const void* tgt = d_in[0];
    const void* mem = d_in[1];
    const void* sWq = d_in[2];  const void* sWk = d_in[3];
    const void* sWv = d_in[4];  const void* sWo = d_in[5];
    const void* cWq = d_in[6];  const void* cWk = d_in[7];
    const void* cWv = d_in[8];  const void* cWo = d_in[9];
    const void* sbq = d_in[10]; const void* sbk = d_in[11];
    const void* sbv = d_in[12]; const void* sbo = d_in[13];
    const void* cbq = d_in[14]; const void* cbk = d_in[15];
    const void* cbv = d_in[16]; const void* cbo = d_in[17];
    const void* fW1 = d_in[18]; const void* fb1 = d_in[19];
    const void* fW2 = d_in[20]; const void* fb2 = d_in[21];
    const void* g1  = d_in[22]; const void* g2  = d_in[23];
    const void* g3  = d_in[24];
    const void* be1 = d_in[25]; const void* be2 = d_in[26];
    const void* be3 = d_in[27];

    char* ws = (char*)d_ws;
    const size_t MB = 1048576;
    ushort_t* qkv = (ushort_t*)(ws + 0 * MB);
    ushort_t* hb  = (ushort_t*)(ws + 0 * MB);    // FFN hidden [4096][2048]
    ushort_t* pA  = (ushort_t*)(ws + 12 * MB);   // o-proj partial A
    ushort_t* xb  = (ushort_t*)(ws + 16 * MB);
    ushort_t* tb  = (ushort_t*)(ws + 20 * MB);
    ushort_t* mb  = (ushort_t*)(ws + 24 * MB);
    ushort_t* pB  = (ushort_t*)(ws + 20 * MB);   // o-proj partial B (tb region)
    ushort_t* ofA = (ushort_t*)(ws + 20 * MB);   // FFN2 partial A
    ushort_t* ofB = (ushort_t*)(ws + 24 * MB);   // FFN2 partial B
    ushort_t* wb  = (ushort_t*)(ws + 28 * MB);
    float*    pb  = (float*)   (ws + 36 * MB);
    int*   dflag  = (int*)     (ws + 36 * MB + 262144);

    const ushort_t* sWqkv_t = wb + 0;
    const ushort_t* sWo_t   = wb + 786432;
    const ushort_t* cWqkv_t = wb + 1048576;
    const ushort_t* cWo_t   = wb + 1835008;
    const ushort_t* fW1_t   = wb + 2097152;
    const ushort_t* fW2_t   = wb + 3145728;

    dim3 blk(256);

    int mode;
    if (in_sizes[0] == 4 * 1024 * 512 * 4)      mode = 0;   // f32
    else if (in_sizes[0] == 4 * 1024 * 512 * 2) mode = 1;   // bf16
    else                                        mode = 2;   // detect on device
    if (mode == 2)
        detect_dtype<<<dim3(1), blk, 0, stream>>>((const ushort_t*)tgt, dflag);

    prep_all<<<dim3(3098), blk, 0, stream>>>(
        sWq, sWk, sWv, sWo, cWq, cWk, cWv, cWo, fW1, fW2,
        tgt, mem, sbq, sbk, sbv, sbo, cbq, cbk, cbv, cbo, fb1, fb2,
        wb, tb, mb, pb, mode, dflag);

    dim3 gattn(16, 32);
    dim3 blk512(512);

    // ---- self-attention ----
    gemm_tn<ushort_t, false, 64, 128, false><<<dim3(64, 12), blk, 0, stream>>>(
        tb, tb, 0, 512, sWqkv_t, 512, pb + 0, qkv, 1536, 512, (ushort_t*)nullptr);
    attn_mfma<<<gattn, blk512, 0, stream>>>(qkv);
    gemm_tn<ushort_t, false, 64, 64, true><<<dim3(64, 8, 2), blk, 0, stream>>>(
        qkv, qkv, 0, 1536, sWo_t, 512, pb + 1536, pA, 512, 256, pB);
    ln_kernel<true, false><<<dim3(4096), blk, 0, stream>>>(
        tgt, pA, pB, g1, be1, xb, mode, dflag);

    // ---- cross-attention ----
    gemm_tn<ushort_t, false, 64, 128, false><<<dim3(64, 12), blk, 0, stream>>>(
        xb, mb, 4, 512, cWqkv_t, 512, pb + 2048, qkv, 1536, 512, (ushort_t*)nullptr);
    attn_mfma<<<gattn, blk512, 0, stream>>>(qkv);
    gemm_tn<ushort_t, false, 64, 64, true><<<dim3(64, 8, 2), blk, 0, stream>>>(
        qkv, qkv, 0, 1536, cWo_t, 512, pb + 3584, pA, 512, 256, pB);
    ln_kernel<false, false><<<dim3(4096), blk, 0, stream>>>(
        xb, pA, pB, g2, be2, xb, mode, dflag);

    // ---- FFN ----
    gemm_tn<ushort_t, true, 128, 128, false><<<dim3(32, 16), blk, 0, stream>>>(
        xb, xb, 0, 512, fW1_t, 512, pb + 4096, hb, 2048, 512, (ushort_t*)nullptr);
    gemm_tn<ushort_t, false, 64, 64, true><<<dim3(64, 8, 2), blk, 0, stream>>>(
        hb, hb, 0, 2048, fW2_t, 2048, pb + 6144, ofA, 512, 1024, ofB);
    ln_kernel<false, true><<<dim3(4096), blk, 0, stream>>>(
        xb, ofA, ofB, g3, be3, d_out, mode, dflag);
}